// Round 13
// baseline (624.851 us; speedup 1.0000x reference)
//
#include <hip/hip_runtime.h>
#include <hip/hip_cooperative_groups.h>
#include <hip/hip_bf16.h>

namespace cg = cooperative_groups;

#define NEG_INF -9.0e15f

using u16 = unsigned short;

__device__ __forceinline__ float b2f(__hip_bfloat16 v) { return __bfloat162float(v); }
__device__ __forceinline__ float ldv(const float* p, int i) { return p[i]; }
__device__ __forceinline__ float ldv(const __hip_bfloat16* p, int i) { return __bfloat162float(p[i]); }

__device__ __forceinline__ void unpack8u(uint4 r, float* f) {
    f[0]=__uint_as_float(r.x<<16); f[1]=__uint_as_float(r.x&0xffff0000u);
    f[2]=__uint_as_float(r.y<<16); f[3]=__uint_as_float(r.y&0xffff0000u);
    f[4]=__uint_as_float(r.z<<16); f[5]=__uint_as_float(r.z&0xffff0000u);
    f[6]=__uint_as_float(r.w<<16); f[7]=__uint_as_float(r.w&0xffff0000u);
}
__device__ __forceinline__ void ld8w(const __hip_bfloat16* p, int idx, float* f) {
    unpack8u(*(const uint4*)(p + idx), f);
}
__device__ __forceinline__ void ld8w(const float* p, int idx, float* f) {
    const float4* q = (const float4*)(p + idx);
    float4 a = q[0], b = q[1];
    f[0]=a.x; f[1]=a.y; f[2]=a.z; f[3]=a.w; f[4]=b.x; f[5]=b.y; f[6]=b.z; f[7]=b.w;
}

__device__ __forceinline__ void async16(const void* g, void* l) {
    __builtin_amdgcn_global_load_lds(
        (__attribute__((address_space(1))) void*)(g),
        (__attribute__((address_space(3))) void*)(l), 16, 0, 0);
}

// wave-level dtype sniff (uniform per wave): bf16 weights -> sane exponents.
__device__ __forceinline__ int sniff(const void* wnode) {
    const u16* w = (const u16*)wnode;
    int lane = threadIdx.x & 63;
    u16 u = w[2 * lane];
    int e = (u >> 7) & 0xFF;
    unsigned long long m = __ballot(e >= 100 && e <= 140);
    return __popcll(m) >= 48;
}

// ---- Phase-B GEMM: h[row0+r] = xsT_row @ W ; s1/s2 epilogue ---------------
// 256 thr: r = t>>5 (8 rows), cols 8*(t&31). xsT layout [k][8] (k*8+r).
template <typename T>
__device__ __forceinline__ void gemm_phase(
    const float* __restrict__ xsT, const T* __restrict__ Wl,
    const T* __restrict__ ga, int t, int row0,
    float* __restrict__ h_out, float* __restrict__ s1_out, float* __restrict__ s2_out) {
    const int r = t >> 5, cg = t & 31, c0 = 8 * cg;
    float g0[8];
    #pragma unroll
    for (int j = 0; j < 8; ++j) g0[j] = 0.f;
    #pragma unroll 4
    for (int k = 0; k < 256; ++k) {
        float w8[8];
        ld8w(Wl, k * 256 + c0, w8);
        float xv = xsT[k * 8 + r];
        #pragma unroll
        for (int j = 0; j < 8; ++j) g0[j] += xv * w8[j];
    }
    float a1v[8], a2v[8];
    ld8w(ga, c0, a1v);
    ld8w(ga, 256 + c0, a2v);
    float d1 = 0.f, d2 = 0.f;
    #pragma unroll
    for (int j = 0; j < 8; ++j) { d1 += g0[j] * a1v[j]; d2 += g0[j] * a2v[j]; }
    #pragma unroll
    for (int off = 1; off < 32; off <<= 1) {   // reduce within each 32-lane half
        d1 += __shfl_xor(d1, off, 64);
        d2 += __shfl_xor(d2, off, 64);
    }
    if (cg == 0) { s1_out[row0 + r] = d1; s2_out[row0 + r] = d2; }
    *(float4*)&h_out[(size_t)(row0 + r) * 256 + c0]     = (float4){g0[0], g0[1], g0[2], g0[3]};
    *(float4*)&h_out[(size_t)(row0 + r) * 256 + c0 + 4] = (float4){g0[4], g0[5], g0[6], g0[7]};
}

// ---- P0 prologue: xsT <- (nf @ Wn + b) transposed -------------------------
template <typename T>
__device__ __forceinline__ void build_x0(
    const T* __restrict__ nfp, const T* __restrict__ Wn, const T* __restrict__ bn,
    int t, int row0, float* __restrict__ xsT, float* __restrict__ nfs) {
    for (int i = t; i < 624; i += 256) {
        int r = i / 78, k = i - r * 78;
        nfs[r * 80 + k] = ldv(nfp, (row0 + r) * 78 + k);
    }
    __syncthreads();
    const int r = t >> 5, cg = t & 31, c0 = 8 * cg;
    float acc[8];
    ld8w(bn, c0, acc);
    #pragma unroll 2
    for (int k = 0; k < 78; ++k) {
        float w8[8];
        ld8w(Wn, k * 256 + c0, w8);
        float xv = nfs[r * 80 + k];
        #pragma unroll
        for (int j = 0; j < 8; ++j) acc[j] += xv * w8[j];
    }
    #pragma unroll
    for (int j = 0; j < 8; ++j) xsT[(c0 + j) * 8 + r] = acc[j];
    __syncthreads();
}

// ---- fused attn phase: softmax + att@h -> xsT (relu'd, transposed) --------
__device__ __forceinline__ void fused_attn(
    const float* __restrict__ h_in, const float* __restrict__ s1_in,
    const float* __restrict__ s2_in, const int* __restrict__ adj,
    int blk, int t, float* __restrict__ att_t, float* __restrict__ hbuf,
    float* __restrict__ xsT) {
    int b = blk >> 4, i0 = (blk & 15) << 3;
    int w = t >> 6, lane = t & 63;
    const char* hbytes = (const char*)(h_in + (size_t)b * 32768);
    const int ph = blk & 7;
    {   // stage chunk ph (16 rows = 16 KB)
        char* lb = (char*)hbuf;
        const char* g = hbytes + ph * 16384;
        #pragma unroll
        for (int i = 0; i < 4; ++i)
            async16(g + i * 4096 + t * 16, lb + i * 4096 + t * 16);
    }
    {   // softmax: wave w owns rows 2w, 2w+1
        int cc0 = lane, cc1 = lane + 64;
        int ir0 = i0 + 2 * w, ir1 = ir0 + 1;
        const int* a0 = adj + (size_t)(b * 128 + ir0) * 128;
        const int* a1 = adj + (size_t)(b * 128 + ir1) * 128;
        int m00 = a0[cc0], m01 = a0[cc1], m10 = a1[cc0], m11 = a1[cc1];
        float sv0 = s1_in[b * 128 + ir0], sv1 = s1_in[b * 128 + ir1];
        float t0 = s2_in[b * 128 + cc0],  t1 = s2_in[b * 128 + cc1];
        float e00 = sv0 + t0; e00 = (e00 >= 0.f) ? e00 : 0.2f * e00;
        float e01 = sv0 + t1; e01 = (e01 >= 0.f) ? e01 : 0.2f * e01;
        float e10 = sv1 + t0; e10 = (e10 >= 0.f) ? e10 : 0.2f * e10;
        float e11 = sv1 + t1; e11 = (e11 >= 0.f) ? e11 : 0.2f * e11;
        float v00 = (m00 > 0) ? e00 : NEG_INF;
        float v01 = (m01 > 0) ? e01 : NEG_INF;
        float v10 = (m10 > 0) ? e10 : NEG_INF;
        float v11 = (m11 > 0) ? e11 : NEG_INF;
        float mx0 = fmaxf(v00, v01), mx1 = fmaxf(v10, v11);
        #pragma unroll
        for (int off = 1; off < 64; off <<= 1) {
            mx0 = fmaxf(mx0, __shfl_xor(mx0, off, 64));
            mx1 = fmaxf(mx1, __shfl_xor(mx1, off, 64));
        }
        float p00 = __expf(v00 - mx0), p01 = __expf(v01 - mx0);
        float p10 = __expf(v10 - mx1), p11 = __expf(v11 - mx1);
        float s0 = p00 + p01, ss1 = p10 + p11;
        #pragma unroll
        for (int off = 1; off < 64; off <<= 1) {
            s0  += __shfl_xor(s0, off, 64);
            ss1 += __shfl_xor(ss1, off, 64);
        }
        float inv0 = 1.0f / s0, inv1 = 1.0f / ss1;
        att_t[cc0 * 10 + 2 * w]     = p00 * inv0;
        att_t[cc1 * 10 + 2 * w]     = p01 * inv0;
        att_t[cc0 * 10 + 2 * w + 1] = p10 * inv1;
        att_t[cc1 * 10 + 2 * w + 1] = p11 * inv1;
    }
    __syncthreads();
    int tx = t & 63, ty = t >> 6;
    float acc0[4] = {0.f, 0.f, 0.f, 0.f}, acc1[4] = {0.f, 0.f, 0.f, 0.f};
    for (int c = 0; c < 8; ++c) {
        if (c < 7) {
            char* lb = (char*)hbuf + ((c + 1) & 1) * 16384;
            const char* g = hbytes + (((c + 1 + ph) & 7) * 16384);
            #pragma unroll
            for (int i = 0; i < 4; ++i)
                async16(g + i * 4096 + t * 16, lb + i * 4096 + t * 16);
        }
        const float* hc = hbuf + (c & 1) * 4096;
        const int jb = ((c + ph) & 7) * 16;
        #pragma unroll 4
        for (int jj = 0; jj < 16; ++jj) {
            float4 hv = *(const float4*)&hc[jj * 256 + 4 * tx];
            float2 ap = *(const float2*)&att_t[(jb + jj) * 10 + 2 * ty];
            acc0[0] += ap.x * hv.x; acc0[1] += ap.x * hv.y;
            acc0[2] += ap.x * hv.z; acc0[3] += ap.x * hv.w;
            acc1[0] += ap.y * hv.x; acc1[1] += ap.y * hv.y;
            acc1[2] += ap.y * hv.z; acc1[3] += ap.y * hv.w;
        }
        __syncthreads();
    }
    #pragma unroll
    for (int j = 0; j < 4; ++j) {
        xsT[(4 * tx + j) * 8 + 2 * ty]     = fmaxf(acc0[j], 0.f);
        xsT[(4 * tx + j) * 8 + 2 * ty + 1] = fmaxf(acc1[j], 0.f);
    }
    __syncthreads();
}

// ---- args ------------------------------------------------------------------
struct GnnArgs {
    const void* nf; const int* adj;
    const void* W_node; const void* b_node;
    const void* gat_W; const void* gat_a;
    float* hA; float* hB;
    float* s1A; float* s2A; float* s1B; float* s2B;
    float* gpart;
};

// ---- mega kernel: P0 gat0 | P1 attn0+gat1 | P2 attn1+gat2 | P3 attn2+pool --
__global__ __launch_bounds__(256) void k_gnn(GnnArgs a) {
    cg::grid_group grid = cg::this_grid();
    __shared__ __align__(16) char smem[74752];
    float* att_t = (float*)smem;                  // 5120 B   [128][10]
    float* hbuf  = (float*)(smem + 5120);         // 32 KB (P1/P2) / 64 KB (P3)
    float* xsT   = (float*)(smem + 37888);        // 8 KB     [256][8]
    float* nfs   = (float*)(smem + 46080);        // 2560 B   [8][80]
    float* pool_red = (float*)(smem + 70656);     // 4 KB     [4][256]

    const int t = threadIdx.x, blk = blockIdx.x;
    const int row0 = blk * 8;
    const int isbf = sniff(a.W_node);

    // ---------------- P0 ----------------
    if (isbf) {
        build_x0<__hip_bfloat16>((const __hip_bfloat16*)a.nf,
                                 (const __hip_bfloat16*)a.W_node,
                                 (const __hip_bfloat16*)a.b_node, t, row0, xsT, nfs);
        gemm_phase<__hip_bfloat16>(xsT, (const __hip_bfloat16*)a.gat_W,
                                   (const __hip_bfloat16*)a.gat_a, t, row0,
                                   a.hA, a.s1A, a.s2A);
    } else {
        build_x0<float>((const float*)a.nf, (const float*)a.W_node,
                        (const float*)a.b_node, t, row0, xsT, nfs);
        gemm_phase<float>(xsT, (const float*)a.gat_W, (const float*)a.gat_a,
                          t, row0, a.hA, a.s1A, a.s2A);
    }
    __threadfence();
    grid.sync();

    // ---------------- P1: attn0 + gat1 ----------------
    fused_attn(a.hA, a.s1A, a.s2A, a.adj, blk, t, att_t, hbuf, xsT);
    if (isbf) {
        gemm_phase<__hip_bfloat16>(xsT, (const __hip_bfloat16*)a.gat_W + 65536,
                                   (const __hip_bfloat16*)a.gat_a + 512, t, row0,
                                   a.hB, a.s1B, a.s2B);
    } else {
        gemm_phase<float>(xsT, (const float*)a.gat_W + 65536,
                          (const float*)a.gat_a + 512, t, row0,
                          a.hB, a.s1B, a.s2B);
    }
    __threadfence();
    grid.sync();

    // ---------------- P2: attn1 + gat2 ----------------
    fused_attn(a.hB, a.s1B, a.s2B, a.adj, blk, t, att_t, hbuf, xsT);
    if (isbf) {
        gemm_phase<__hip_bfloat16>(xsT, (const __hip_bfloat16*)a.gat_W + 131072,
                                   (const __hip_bfloat16*)a.gat_a + 1024, t, row0,
                                   a.hA, a.s1A, a.s2A);
    } else {
        gemm_phase<float>(xsT, (const float*)a.gat_W + 131072,
                          (const float*)a.gat_a + 1024, t, row0,
                          a.hA, a.s1A, a.s2A);
    }
    __threadfence();
    grid.sync();

    // ---------------- P3: attn2 + mean-pool partials ----------------
    {
        int b = blk >> 4, i0 = (blk & 15) << 3;
        int w = t >> 6, lane = t & 63;
        const char* hbytes = (const char*)(a.hA + (size_t)b * 32768);
        const int ph = blk & 3;
        {
            char* lb = (char*)hbuf;
            const char* g = hbytes + ph * 32768;
            #pragma unroll
            for (int i = 0; i < 8; ++i)
                async16(g + i * 4096 + t * 16, lb + i * 4096 + t * 16);
        }
        {
            int cc0 = lane, cc1 = lane + 64;
            int ir0 = i0 + 2 * w, ir1 = ir0 + 1;
            const int* a0 = a.adj + (size_t)(b * 128 + ir0) * 128;
            const int* a1 = a.adj + (size_t)(b * 128 + ir1) * 128;
            int m00 = a0[cc0], m01 = a0[cc1], m10 = a1[cc0], m11 = a1[cc1];
            float sv0 = a.s1A[b * 128 + ir0], sv1 = a.s1A[b * 128 + ir1];
            float t0 = a.s2A[b * 128 + cc0],  t1 = a.s2A[b * 128 + cc1];
            float e00 = sv0 + t0; e00 = (e00 >= 0.f) ? e00 : 0.2f * e00;
            float e01 = sv0 + t1; e01 = (e01 >= 0.f) ? e01 : 0.2f * e01;
            float e10 = sv1 + t0; e10 = (e10 >= 0.f) ? e10 : 0.2f * e10;
            float e11 = sv1 + t1; e11 = (e11 >= 0.f) ? e11 : 0.2f * e11;
            float v00 = (m00 > 0) ? e00 : NEG_INF;
            float v01 = (m01 > 0) ? e01 : NEG_INF;
            float v10 = (m10 > 0) ? e10 : NEG_INF;
            float v11 = (m11 > 0) ? e11 : NEG_INF;
            float mx0 = fmaxf(v00, v01), mx1 = fmaxf(v10, v11);
            #pragma unroll
            for (int off = 1; off < 64; off <<= 1) {
                mx0 = fmaxf(mx0, __shfl_xor(mx0, off, 64));
                mx1 = fmaxf(mx1, __shfl_xor(mx1, off, 64));
            }
            float p00 = __expf(v00 - mx0), p01 = __expf(v01 - mx0);
            float p10 = __expf(v10 - mx1), p11 = __expf(v11 - mx1);
            float s0 = p00 + p01, ss1 = p10 + p11;
            #pragma unroll
            for (int off = 1; off < 64; off <<= 1) {
                s0  += __shfl_xor(s0, off, 64);
                ss1 += __shfl_xor(ss1, off, 64);
            }
            float inv0 = 1.0f / s0, inv1 = 1.0f / ss1;
            att_t[cc0 * 10 + 2 * w]     = p00 * inv0;
            att_t[cc1 * 10 + 2 * w]     = p01 * inv0;
            att_t[cc0 * 10 + 2 * w + 1] = p10 * inv1;
            att_t[cc1 * 10 + 2 * w + 1] = p11 * inv1;
        }
        __syncthreads();
        int tx = t & 63, ty = t >> 6;
        float acc0[4] = {0.f, 0.f, 0.f, 0.f}, acc1[4] = {0.f, 0.f, 0.f, 0.f};
        for (int c = 0; c < 4; ++c) {
            if (c < 3) {
                char* lb = (char*)hbuf + ((c + 1) & 1) * 32768;
                const char* g = hbytes + (((c + 1 + ph) & 3) * 32768);
                #pragma unroll
                for (int i = 0; i < 8; ++i)
                    async16(g + i * 4096 + t * 16, lb + i * 4096 + t * 16);
            }
            const float* hc = hbuf + (c & 1) * 8192;
            const int jb = ((c + ph) & 3) * 32;
            #pragma unroll 4
            for (int jj = 0; jj < 32; ++jj) {
                float4 hv = *(const float4*)&hc[jj * 256 + 4 * tx];
                float2 ap = *(const float2*)&att_t[(jb + jj) * 10 + 2 * ty];
                acc0[0] += ap.x * hv.x; acc0[1] += ap.x * hv.y;
                acc0[2] += ap.x * hv.z; acc0[3] += ap.x * hv.w;
                acc1[0] += ap.y * hv.x; acc1[1] += ap.y * hv.y;
                acc1[2] += ap.y * hv.z; acc1[3] += ap.y * hv.w;
            }
            __syncthreads();
        }
        float4 pr = {(fmaxf(acc0[0],0.f) + fmaxf(acc1[0],0.f)) * (1.f/128.f),
                     (fmaxf(acc0[1],0.f) + fmaxf(acc1[1],0.f)) * (1.f/128.f),
                     (fmaxf(acc0[2],0.f) + fmaxf(acc1[2],0.f)) * (1.f/128.f),
                     (fmaxf(acc0[3],0.f) + fmaxf(acc1[3],0.f)) * (1.f/128.f)};
        *(float4*)&pool_red[ty * 256 + 4 * tx] = pr;
        __syncthreads();
        if (t < 64) {
            float4 r0 = ((const float4*)&pool_red[0])[t];
            float4 r1 = ((const float4*)&pool_red[256])[t];
            float4 r2 = ((const float4*)&pool_red[512])[t];
            float4 r3 = ((const float4*)&pool_red[768])[t];
            float4 o = {r0.x+r1.x+r2.x+r3.x, r0.y+r1.y+r2.y+r3.y,
                        r0.z+r1.z+r2.z+r3.z, r0.w+r1.w+r2.w+r3.w};
            *(float4*)&a.gpart[((size_t)b * 16 + (blk & 15)) * 256 + 4 * t] = o;
        }
    }
}

// ---------------- head: pool MLPs + concat + out MLP ------------------------
template <typename T>
__device__ __forceinline__ void head_body(
    int b, int t, const float* __restrict__ gpart,
    const T* scaf, const T* W_sc, const T* b_sc,
    const T* gp_w1, const T* gp_b1, const T* gp_w2, const T* gp_b2,
    const T* out_w1, const T* out_b1, const T* out_w2, const T* out_b2,
    float* gin_s, float* sproj, float* scaf_s,
    float* red1, float* red2, float* z1g, float* z1s,
    float* cvec, float* hdn, float* outv) {
    float g = 0.f;
    #pragma unroll
    for (int gg = 0; gg < 16; ++gg) g += gpart[((size_t)b * 16 + gg) * 256 + t];
    gin_s[t] = g;
    if (t < 20) scaf_s[t] = ldv(scaf, b * 20 + t);
    __syncthreads();
    {
        float sa = ldv(b_sc, t);
        #pragma unroll
        for (int k = 0; k < 20; ++k) sa += scaf_s[k] * ldv(W_sc, k * 256 + t);
        sproj[t] = sa;
    }
    __syncthreads();
    {
        int j = t & 127, khalf = t >> 7;
        int k0 = khalf * 128;
        float a1 = 0.f, a2 = 0.f;
        #pragma unroll 16
        for (int kk = 0; kk < 128; ++kk) {
            int k = k0 + kk;
            float wv = ldv(gp_w1, k * 128 + j);
            a1 += gin_s[k] * wv;
            a2 += sproj[k] * wv;
        }
        red1[t] = a1; red2[t] = a2;
    }
    __syncthreads();
    if (t < 128) {
        float bb = ldv(gp_b1, t);
        z1g[t] = fmaxf(bb + red1[t] + red1[t + 128], 0.f);
        z1s[t] = fmaxf(bb + red2[t] + red2[t + 128], 0.f);
    }
    __syncthreads();
    {
        int j = t & 63, q = t >> 6;
        int k0 = q * 32;
        float a1 = 0.f, a2 = 0.f;
        #pragma unroll
        for (int kk = 0; kk < 32; ++kk) {
            int k = k0 + kk;
            float wv = ldv(gp_w2, k * 64 + j);
            a1 += z1g[k] * wv;
            a2 += z1s[k] * wv;
        }
        red1[t] = a1; red2[t] = a2;
    }
    __syncthreads();
    if (t < 64) {
        float bb = ldv(gp_b2, t);
        cvec[t]      = fmaxf(bb + red1[t] + red1[t + 64] + red1[t + 128] + red1[t + 192], 0.f);
        cvec[64 + t] = fmaxf(bb + red2[t] + red2[t + 64] + red2[t + 128] + red2[t + 192], 0.f);
    }
    __syncthreads();
    {
        int j = t & 127, khalf = t >> 7;
        int k0 = khalf * 64;
        float a = 0.f;
        #pragma unroll 16
        for (int kk = 0; kk < 64; ++kk) {
            int k = k0 + kk;
            a += cvec[k] * ldv(out_w1, k * 128 + j);
        }
        red1[t] = a;
    }
    __syncthreads();
    if (t < 128) hdn[t] = fmaxf(ldv(out_b1, t) + red1[t] + red1[t + 128], 0.f);
    __syncthreads();
    if (t < 13) {
        float a = ldv(out_b2, t);
        #pragma unroll 16
        for (int k = 0; k < 128; ++k) a += hdn[k] * ldv(out_w2, k * 13 + t);
        outv[t] = a;
    }
}

__global__ __launch_bounds__(256) void k_head(
    const float* __restrict__ gpart, const void* __restrict__ scaf,
    const void* __restrict__ W_sc, const void* __restrict__ b_sc,
    const void* __restrict__ gp_w1, const void* __restrict__ gp_b1,
    const void* __restrict__ gp_w2, const void* __restrict__ gp_b2,
    const void* __restrict__ out_w1, const void* __restrict__ out_b1,
    const void* __restrict__ out_w2, const void* __restrict__ out_b2,
    void* __restrict__ out, const void* __restrict__ Wn) {
    int isbf = sniff(Wn);
    int b = blockIdx.x;
    int t = threadIdx.x;
    __shared__ float gin_s[256], sproj[256], scaf_s[20];
    __shared__ float red1[256], red2[256];
    __shared__ float z1g[128], z1s[128], cvec[128], hdn[128], outv[13];
    if (isbf) {
        head_body<__hip_bfloat16>(b, t, gpart,
            (const __hip_bfloat16*)scaf, (const __hip_bfloat16*)W_sc, (const __hip_bfloat16*)b_sc,
            (const __hip_bfloat16*)gp_w1, (const __hip_bfloat16*)gp_b1,
            (const __hip_bfloat16*)gp_w2, (const __hip_bfloat16*)gp_b2,
            (const __hip_bfloat16*)out_w1, (const __hip_bfloat16*)out_b1,
            (const __hip_bfloat16*)out_w2, (const __hip_bfloat16*)out_b2,
            gin_s, sproj, scaf_s, red1, red2, z1g, z1s, cvec, hdn, outv);
    } else {
        head_body<float>(b, t, gpart,
            (const float*)scaf, (const float*)W_sc, (const float*)b_sc,
            (const float*)gp_w1, (const float*)gp_b1,
            (const float*)gp_w2, (const float*)gp_b2,
            (const float*)out_w1, (const float*)out_b1,
            (const float*)out_w2, (const float*)out_b2,
            gin_s, sproj, scaf_s, red1, red2, z1g, z1s, cvec, hdn, outv);
    }
    __syncthreads();
    if (t < 13) {
        if (isbf) ((__hip_bfloat16*)out)[b * 13 + t] = __float2bfloat16(outv[t]);
        else      ((float*)out)[b * 13 + t] = outv[t];
    }
}

extern "C" void kernel_launch(void* const* d_in, const int* in_sizes, int n_in,
                              void* d_out, int out_size, void* d_ws, size_t ws_size,
                              hipStream_t stream) {
    (void)in_sizes; (void)n_in; (void)out_size; (void)ws_size;
    const void* nf     = d_in[0];
    const int*  adj    = (const int*)d_in[2];
    const void* scaf   = d_in[3];
    const void* W_node = d_in[4];
    const void* b_node = d_in[5];
    const void* gat_W  = d_in[6];
    const void* gat_a  = d_in[7];
    const void* W_sc   = d_in[8];
    const void* b_sc   = d_in[9];
    const void* gp_w1  = d_in[10];
    const void* gp_b1  = d_in[11];
    const void* gp_w2  = d_in[12];
    const void* gp_b2  = d_in[13];
    const void* out_w1 = d_in[14];
    const void* out_b1 = d_in[15];
    const void* out_w2 = d_in[16];
    const void* out_b2 = d_in[17];

    float* ws    = (float*)d_ws;
    float* hA    = ws;                      // 1048576 f32
    float* hB    = ws + 1048576;            // 1048576 f32
    float* s1A   = ws + 2097152;            // 4096
    float* s2A   = s1A + 4096;
    float* s1B   = s2A + 4096;
    float* s2B   = s1B + 4096;
    float* gpart = s2B + 4096;              // 131072

    GnnArgs ha;
    ha.nf = nf; ha.adj = adj;
    ha.W_node = W_node; ha.b_node = b_node;
    ha.gat_W = gat_W; ha.gat_a = gat_a;
    ha.hA = hA; ha.hB = hB;
    ha.s1A = s1A; ha.s2A = s2A; ha.s1B = s1B; ha.s2B = s2B;
    ha.gpart = gpart;
    void* kargs[] = { (void*)&ha };
    hipLaunchCooperativeKernel((const void*)k_gnn, dim3(512), dim3(256),
                               kargs, 0, stream);
    k_head<<<32, 256, 0, stream>>>(gpart, scaf, W_sc, b_sc, gp_w1, gp_b1, gp_w2, gp_b2,
                                   out_w1, out_b1, out_w2, out_b2, d_out, W_node);
}

// Round 14
// 220.089 us; speedup vs baseline: 2.8391x; 2.8391x over previous
//
#include <hip/hip_runtime.h>
#include <hip/hip_bf16.h>

#define NEG_INF -9.0e15f

using u16 = unsigned short;

__device__ __forceinline__ float b2f(__hip_bfloat16 v) { return __bfloat162float(v); }
__device__ __forceinline__ float ldv(const float* p, int i) { return p[i]; }
__device__ __forceinline__ float ldv(const __hip_bfloat16* p, int i) { return __bfloat162float(p[i]); }

__device__ __forceinline__ void async16(const void* g, void* l) {
    __builtin_amdgcn_global_load_lds(
        (__attribute__((address_space(1))) void*)(g),
        (__attribute__((address_space(3))) void*)(l), 16, 0, 0);
}

// wave-level dtype sniff (uniform per wave): bf16 weights -> sane exponents.
__device__ __forceinline__ int sniff(const void* wnode) {
    const u16* w = (const u16*)wnode;
    int lane = threadIdx.x & 63;
    u16 u = w[2 * lane];
    int e = (u >> 7) & 0xFF;
    unsigned long long m = __ballot(e >= 100 && e <= 140);
    return __popcll(m) >= 48;
}

// -------- k_gat: h = x@W[l]; s1 = h@a1; s2 = h@a2 -- round-9 structure -----
// 512 blocks x 256 thr. Block = 8 rows x 256 cols. Thread: rows {2w,2w+1}
// (w = wave = t>>6), cols 4tx..4tx+3 (tx = t&63). W direct from global,
// x broadcast from stride-10 LDS transpose. No barriers in the k-loop.
__global__ __launch_bounds__(256) void k_gat(
    const float* __restrict__ x, const void* __restrict__ gat_W,
    const void* __restrict__ gat_a, int layer,
    const void* __restrict__ nf, const void* __restrict__ Wn_raw,
    const void* __restrict__ bn, int first,
    float* __restrict__ h, float* __restrict__ s1, float* __restrict__ s2) {
    __shared__ float xsT[256 * 10];     // [k][row(8) pad 10]
    const int t = threadIdx.x;
    const int bx = blockIdx.x;
    const int row0 = bx * 8;
    const int tx = t & 63, w = t >> 6;  // wave w handles rows 2w, 2w+1
    const int isbf = sniff(Wn_raw);
    const int c0 = 4 * tx;

    float acc0[4], acc1[4];

    if (isbf) {
        if (first) {
            // stage nf rows transposed: nfsT[k][r] (reuse xsT, k<78)
            const u16* nfu = (const u16*)nf;
            for (int i = t; i < 624; i += 256) {
                int r = i / 78, k = i - r * 78;
                xsT[k * 10 + r] = __uint_as_float(((unsigned)nfu[(row0 + r) * 78 + k]) << 16);
            }
            __syncthreads();
            const u16* Wnl = (const u16*)Wn_raw;
            const __hip_bfloat16* bnb = (const __hip_bfloat16*)bn;
            #pragma unroll
            for (int j = 0; j < 4; ++j) { acc0[j] = b2f(bnb[c0 + j]); acc1[j] = acc0[j]; }
            #pragma unroll 2
            for (int k = 0; k < 78; ++k) {
                uint2 wv = *(const uint2*)(Wnl + k * 256 + c0);
                float w0 = __uint_as_float(wv.x << 16);
                float w1 = __uint_as_float(wv.x & 0xffff0000u);
                float w2 = __uint_as_float(wv.y << 16);
                float w3 = __uint_as_float(wv.y & 0xffff0000u);
                float2 xp = *(const float2*)&xsT[k * 10 + 2 * w];
                acc0[0] += xp.x * w0; acc0[1] += xp.x * w1;
                acc0[2] += xp.x * w2; acc0[3] += xp.x * w3;
                acc1[0] += xp.y * w0; acc1[1] += xp.y * w1;
                acc1[2] += xp.y * w2; acc1[3] += xp.y * w3;
            }
            __syncthreads();   // done reading nf variant of xsT
            #pragma unroll
            for (int j = 0; j < 4; ++j) {
                xsT[(c0 + j) * 10 + 2 * w]     = acc0[j];
                xsT[(c0 + j) * 10 + 2 * w + 1] = acc1[j];
            }
            __syncthreads();
        } else {
            int r = t >> 5, cb = (t & 31) * 8;
            const float4* xp = (const float4*)(x + (size_t)(row0 + r) * 256 + cb);
            float4 f0 = xp[0], f1 = xp[1];
            xsT[(cb + 0) * 10 + r] = f0.x; xsT[(cb + 1) * 10 + r] = f0.y;
            xsT[(cb + 2) * 10 + r] = f0.z; xsT[(cb + 3) * 10 + r] = f0.w;
            xsT[(cb + 4) * 10 + r] = f1.x; xsT[(cb + 5) * 10 + r] = f1.y;
            xsT[(cb + 6) * 10 + r] = f1.z; xsT[(cb + 7) * 10 + r] = f1.w;
            __syncthreads();
        }
        // main k-loop: barrier-free, direct global W
        const u16* Wl = (const u16*)gat_W + (size_t)layer * 65536;
        #pragma unroll
        for (int j = 0; j < 4; ++j) { acc0[j] = 0.f; acc1[j] = 0.f; }
        #pragma unroll 4
        for (int k = 0; k < 256; ++k) {
            uint2 wv = *(const uint2*)(Wl + k * 256 + c0);
            float w0 = __uint_as_float(wv.x << 16);
            float w1 = __uint_as_float(wv.x & 0xffff0000u);
            float w2 = __uint_as_float(wv.y << 16);
            float w3 = __uint_as_float(wv.y & 0xffff0000u);
            float2 xp = *(const float2*)&xsT[k * 10 + 2 * w];
            acc0[0] += xp.x * w0; acc0[1] += xp.x * w1;
            acc0[2] += xp.x * w2; acc0[3] += xp.x * w3;
            acc1[0] += xp.y * w0; acc1[1] += xp.y * w1;
            acc1[2] += xp.y * w2; acc1[3] += xp.y * w3;
        }
        // epilogue: s1/s2 (full-wave reduce; wave = exactly rows 2w,2w+1)
        const __hip_bfloat16* ga = (const __hip_bfloat16*)gat_a + (size_t)layer * 512;
        float d10 = 0.f, d20 = 0.f, d11 = 0.f, d21 = 0.f;
        #pragma unroll
        for (int j = 0; j < 4; ++j) {
            float a1v = b2f(ga[c0 + j]), a2v = b2f(ga[256 + c0 + j]);
            d10 += acc0[j] * a1v; d20 += acc0[j] * a2v;
            d11 += acc1[j] * a1v; d21 += acc1[j] * a2v;
        }
        #pragma unroll
        for (int off = 1; off < 64; off <<= 1) {
            d10 += __shfl_xor(d10, off, 64); d20 += __shfl_xor(d20, off, 64);
            d11 += __shfl_xor(d11, off, 64); d21 += __shfl_xor(d21, off, 64);
        }
        if (tx == 0) {
            s1[row0 + 2 * w] = d10;     s2[row0 + 2 * w] = d20;
            s1[row0 + 2 * w + 1] = d11; s2[row0 + 2 * w + 1] = d21;
        }
        *(float4*)&h[(size_t)(row0 + 2 * w) * 256 + c0]     = (float4){acc0[0], acc0[1], acc0[2], acc0[3]};
        *(float4*)&h[(size_t)(row0 + 2 * w + 1) * 256 + c0] = (float4){acc1[0], acc1[1], acc1[2], acc1[3]};
    } else {
        // ---------------- f32 fallback (correct, unoptimized) ----------------
        const float* Wlf = (const float*)gat_W + (size_t)layer * 65536;
        const float* gaf = (const float*)gat_a + (size_t)layer * 512;
        if (first) {
            const float* nff = (const float*)nf;
            for (int i = t; i < 624; i += 256) {
                int r = i / 78, k = i - r * 78;
                xsT[k * 10 + r] = nff[(row0 + r) * 78 + k];
            }
            __syncthreads();
            const float* Wnf = (const float*)Wn_raw;
            const float* bnf = (const float*)bn;
            #pragma unroll
            for (int j = 0; j < 4; ++j) { acc0[j] = bnf[c0 + j]; acc1[j] = acc0[j]; }
            for (int k = 0; k < 78; ++k) {
                float4 wf = *(const float4*)(Wnf + k * 256 + c0);
                float2 xp = *(const float2*)&xsT[k * 10 + 2 * w];
                acc0[0] += xp.x * wf.x; acc0[1] += xp.x * wf.y;
                acc0[2] += xp.x * wf.z; acc0[3] += xp.x * wf.w;
                acc1[0] += xp.y * wf.x; acc1[1] += xp.y * wf.y;
                acc1[2] += xp.y * wf.z; acc1[3] += xp.y * wf.w;
            }
            __syncthreads();
            #pragma unroll
            for (int j = 0; j < 4; ++j) {
                xsT[(c0 + j) * 10 + 2 * w]     = acc0[j];
                xsT[(c0 + j) * 10 + 2 * w + 1] = acc1[j];
            }
            __syncthreads();
        } else {
            int r = t >> 5, cb = (t & 31) * 8;
            const float4* xp = (const float4*)(x + (size_t)(row0 + r) * 256 + cb);
            float4 f0 = xp[0], f1 = xp[1];
            xsT[(cb + 0) * 10 + r] = f0.x; xsT[(cb + 1) * 10 + r] = f0.y;
            xsT[(cb + 2) * 10 + r] = f0.z; xsT[(cb + 3) * 10 + r] = f0.w;
            xsT[(cb + 4) * 10 + r] = f1.x; xsT[(cb + 5) * 10 + r] = f1.y;
            xsT[(cb + 6) * 10 + r] = f1.z; xsT[(cb + 7) * 10 + r] = f1.w;
            __syncthreads();
        }
        #pragma unroll
        for (int j = 0; j < 4; ++j) { acc0[j] = 0.f; acc1[j] = 0.f; }
        #pragma unroll 4
        for (int k = 0; k < 256; ++k) {
            float4 wf = *(const float4*)(Wlf + k * 256 + c0);
            float2 xp = *(const float2*)&xsT[k * 10 + 2 * w];
            acc0[0] += xp.x * wf.x; acc0[1] += xp.x * wf.y;
            acc0[2] += xp.x * wf.z; acc0[3] += xp.x * wf.w;
            acc1[0] += xp.y * wf.x; acc1[1] += xp.y * wf.y;
            acc1[2] += xp.y * wf.z; acc1[3] += xp.y * wf.w;
        }
        float d10 = 0.f, d20 = 0.f, d11 = 0.f, d21 = 0.f;
        #pragma unroll
        for (int j = 0; j < 4; ++j) {
            float a1v = gaf[c0 + j], a2v = gaf[256 + c0 + j];
            d10 += acc0[j] * a1v; d20 += acc0[j] * a2v;
            d11 += acc1[j] * a1v; d21 += acc1[j] * a2v;
        }
        #pragma unroll
        for (int off = 1; off < 64; off <<= 1) {
            d10 += __shfl_xor(d10, off, 64); d20 += __shfl_xor(d20, off, 64);
            d11 += __shfl_xor(d11, off, 64); d21 += __shfl_xor(d21, off, 64);
        }
        if (tx == 0) {
            s1[row0 + 2 * w] = d10;     s2[row0 + 2 * w] = d20;
            s1[row0 + 2 * w + 1] = d11; s2[row0 + 2 * w + 1] = d21;
        }
        *(float4*)&h[(size_t)(row0 + 2 * w) * 256 + c0]     = (float4){acc0[0], acc0[1], acc0[2], acc0[3]};
        *(float4*)&h[(size_t)(row0 + 2 * w + 1) * 256 + c0] = (float4){acc1[0], acc1[1], acc1[2], acc1[3]};
    }
}

// ---------------- attn: softmax(mask(leaky(s1+s2))) @ h ---------------------
__global__ __launch_bounds__(256) void k_attn(
    const float* __restrict__ h, const float* __restrict__ s1,
    const float* __restrict__ s2, const int* __restrict__ adj,
    float* __restrict__ x, float* __restrict__ gpart, int do_pool) {
    __shared__ float att_t[128][10];
    __shared__ __align__(16) float hbuf[2][32 * 256];
    __shared__ float pool_red[4][256];
    int blk = blockIdx.x, b = blk >> 4, i0 = (blk & 15) << 3;
    int t = threadIdx.x, w = t >> 6, lane = t & 63;
    const char* hbytes = (const char*)(h + (size_t)b * 32768);
    const int ph = blk & 3;
    {
        char* lb = (char*)&hbuf[0][0];
        const char* g = hbytes + ph * 32768;
        #pragma unroll
        for (int i = 0; i < 8; ++i)
            async16(g + i * 4096 + t * 16, lb + i * 4096 + t * 16);
    }
    {
        int cc0 = lane, cc1 = lane + 64;
        int ir0 = i0 + 2 * w, ir1 = ir0 + 1;
        const int* a0 = adj + (size_t)(b * 128 + ir0) * 128;
        const int* a1 = adj + (size_t)(b * 128 + ir1) * 128;
        int m00 = a0[cc0], m01 = a0[cc1], m10 = a1[cc0], m11 = a1[cc1];
        float sv0 = s1[b * 128 + ir0], sv1 = s1[b * 128 + ir1];
        float t0 = s2[b * 128 + cc0],  t1 = s2[b * 128 + cc1];
        float e00 = sv0 + t0; e00 = (e00 >= 0.f) ? e00 : 0.2f * e00;
        float e01 = sv0 + t1; e01 = (e01 >= 0.f) ? e01 : 0.2f * e01;
        float e10 = sv1 + t0; e10 = (e10 >= 0.f) ? e10 : 0.2f * e10;
        float e11 = sv1 + t1; e11 = (e11 >= 0.f) ? e11 : 0.2f * e11;
        float v00 = (m00 > 0) ? e00 : NEG_INF;
        float v01 = (m01 > 0) ? e01 : NEG_INF;
        float v10 = (m10 > 0) ? e10 : NEG_INF;
        float v11 = (m11 > 0) ? e11 : NEG_INF;
        float mx0 = fmaxf(v00, v01), mx1 = fmaxf(v10, v11);
        #pragma unroll
        for (int off = 1; off < 64; off <<= 1) {
            mx0 = fmaxf(mx0, __shfl_xor(mx0, off, 64));
            mx1 = fmaxf(mx1, __shfl_xor(mx1, off, 64));
        }
        float p00 = __expf(v00 - mx0), p01 = __expf(v01 - mx0);
        float p10 = __expf(v10 - mx1), p11 = __expf(v11 - mx1);
        float s0 = p00 + p01, ss1 = p10 + p11;
        #pragma unroll
        for (int off = 1; off < 64; off <<= 1) {
            s0  += __shfl_xor(s0, off, 64);
            ss1 += __shfl_xor(ss1, off, 64);
        }
        float inv0 = 1.0f / s0, inv1 = 1.0f / ss1;
        att_t[cc0][2 * w]     = p00 * inv0;
        att_t[cc1][2 * w]     = p01 * inv0;
        att_t[cc0][2 * w + 1] = p10 * inv1;
        att_t[cc1][2 * w + 1] = p11 * inv1;
    }
    __syncthreads();
    int tx = t & 63, ty = t >> 6;
    float acc0[4] = {0.f, 0.f, 0.f, 0.f}, acc1[4] = {0.f, 0.f, 0.f, 0.f};
    for (int c = 0; c < 4; ++c) {
        if (c < 3) {
            char* lb = (char*)&hbuf[(c + 1) & 1][0];
            const char* g = hbytes + (((c + 1 + ph) & 3) * 32768);
            #pragma unroll
            for (int i = 0; i < 8; ++i)
                async16(g + i * 4096 + t * 16, lb + i * 4096 + t * 16);
        }
        const float* hc = &hbuf[c & 1][0];
        const int jb = ((c + ph) & 3) * 32;
        #pragma unroll 4
        for (int jj = 0; jj < 32; ++jj) {
            float4 hv = *(const float4*)&hc[jj * 256 + 4 * tx];
            float2 ap = *(const float2*)&att_t[jb + jj][2 * ty];
            acc0[0] += ap.x * hv.x; acc0[1] += ap.x * hv.y;
            acc0[2] += ap.x * hv.z; acc0[3] += ap.x * hv.w;
            acc1[0] += ap.y * hv.x; acc1[1] += ap.y * hv.y;
            acc1[2] += ap.y * hv.z; acc1[3] += ap.y * hv.w;
        }
        __syncthreads();
    }
    if (!do_pool) {
        float4 o0 = {fmaxf(acc0[0],0.f), fmaxf(acc0[1],0.f), fmaxf(acc0[2],0.f), fmaxf(acc0[3],0.f)};
        float4 o1 = {fmaxf(acc1[0],0.f), fmaxf(acc1[1],0.f), fmaxf(acc1[2],0.f), fmaxf(acc1[3],0.f)};
        *(float4*)&x[(size_t)(b * 128 + i0 + 2 * ty)     * 256 + 4 * tx] = o0;
        *(float4*)&x[(size_t)(b * 128 + i0 + 2 * ty + 1) * 256 + 4 * tx] = o1;
    } else {
        float4 pr = {(fmaxf(acc0[0],0.f) + fmaxf(acc1[0],0.f)) * (1.f/128.f),
                     (fmaxf(acc0[1],0.f) + fmaxf(acc1[1],0.f)) * (1.f/128.f),
                     (fmaxf(acc0[2],0.f) + fmaxf(acc1[2],0.f)) * (1.f/128.f),
                     (fmaxf(acc0[3],0.f) + fmaxf(acc1[3],0.f)) * (1.f/128.f)};
        *(float4*)&pool_red[ty][4 * tx] = pr;
        __syncthreads();
        if (t < 64) {
            float4 r0 = ((const float4*)&pool_red[0][0])[t];
            float4 r1 = ((const float4*)&pool_red[1][0])[t];
            float4 r2 = ((const float4*)&pool_red[2][0])[t];
            float4 r3 = ((const float4*)&pool_red[3][0])[t];
            float4 o = {r0.x+r1.x+r2.x+r3.x, r0.y+r1.y+r2.y+r3.y,
                        r0.z+r1.z+r2.z+r3.z, r0.w+r1.w+r2.w+r3.w};
            *(float4*)&gpart[((size_t)b * 16 + (blk & 15)) * 256 + 4 * t] = o;
        }
    }
}

// ---------------- head: pool MLPs + concat + out MLP ------------------------
template <typename T>
__device__ __forceinline__ void head_body(
    int b, int t, const float* __restrict__ gpart,
    const T* scaf, const T* W_sc, const T* b_sc,
    const T* gp_w1, const T* gp_b1, const T* gp_w2, const T* gp_b2,
    const T* out_w1, const T* out_b1, const T* out_w2, const T* out_b2,
    float* gin_s, float* sproj, float* scaf_s,
    float* red1, float* red2, float* z1g, float* z1s,
    float* cvec, float* hdn, float* outv) {
    float g = 0.f;
    #pragma unroll
    for (int gg = 0; gg < 16; ++gg) g += gpart[((size_t)b * 16 + gg) * 256 + t];
    gin_s[t] = g;
    if (t < 20) scaf_s[t] = ldv(scaf, b * 20 + t);
    __syncthreads();
    {
        float sa = ldv(b_sc, t);
        #pragma unroll
        for (int k = 0; k < 20; ++k) sa += scaf_s[k] * ldv(W_sc, k * 256 + t);
        sproj[t] = sa;
    }
    __syncthreads();
    {
        int j = t & 127, khalf = t >> 7;
        int k0 = khalf * 128;
        float a1 = 0.f, a2 = 0.f;
        #pragma unroll 16
        for (int kk = 0; kk < 128; ++kk) {
            int k = k0 + kk;
            float wv = ldv(gp_w1, k * 128 + j);
            a1 += gin_s[k] * wv;
            a2 += sproj[k] * wv;
        }
        red1[t] = a1; red2[t] = a2;
    }
    __syncthreads();
    if (t < 128) {
        float bb = ldv(gp_b1, t);
        z1g[t] = fmaxf(bb + red1[t] + red1[t + 128], 0.f);
        z1s[t] = fmaxf(bb + red2[t] + red2[t + 128], 0.f);
    }
    __syncthreads();
    {
        int j = t & 63, q = t >> 6;
        int k0 = q * 32;
        float a1 = 0.f, a2 = 0.f;
        #pragma unroll
        for (int kk = 0; kk < 32; ++kk) {
            int k = k0 + kk;
            float wv = ldv(gp_w2, k * 64 + j);
            a1 += z1g[k] * wv;
            a2 += z1s[k] * wv;
        }
        red1[t] = a1; red2[t] = a2;
    }
    __syncthreads();
    if (t < 64) {
        float bb = ldv(gp_b2, t);
        cvec[t]      = fmaxf(bb + red1[t] + red1[t + 64] + red1[t + 128] + red1[t + 192], 0.f);
        cvec[64 + t] = fmaxf(bb + red2[t] + red2[t + 64] + red2[t + 128] + red2[t + 192], 0.f);
    }
    __syncthreads();
    {
        int j = t & 127, khalf = t >> 7;
        int k0 = khalf * 64;
        float a = 0.f;
        #pragma unroll 16
        for (int kk = 0; kk < 64; ++kk) {
            int k = k0 + kk;
            a += cvec[k] * ldv(out_w1, k * 128 + j);
        }
        red1[t] = a;
    }
    __syncthreads();
    if (t < 128) hdn[t] = fmaxf(ldv(out_b1, t) + red1[t] + red1[t + 128], 0.f);
    __syncthreads();
    if (t < 13) {
        float a = ldv(out_b2, t);
        #pragma unroll 16
        for (int k = 0; k < 128; ++k) a += hdn[k] * ldv(out_w2, k * 13 + t);
        outv[t] = a;
    }
}

__global__ __launch_bounds__(256) void k_head(
    const float* __restrict__ gpart, const void* __restrict__ scaf,
    const void* __restrict__ W_sc, const void* __restrict__ b_sc,
    const void* __restrict__ gp_w1, const void* __restrict__ gp_b1,
    const void* __restrict__ gp_w2, const void* __restrict__ gp_b2,
    const void* __restrict__ out_w1, const void* __restrict__ out_b1,
    const void* __restrict__ out_w2, const void* __restrict__ out_b2,
    void* __restrict__ out, const void* __restrict__ Wn) {
    int isbf = sniff(Wn);
    int b = blockIdx.x;
    int t = threadIdx.x;
    __shared__ float gin_s[256], sproj[256], scaf_s[20];
    __shared__ float red1[256], red2[256];
    __shared__ float z1g[128], z1s[128], cvec[128], hdn[128], outv[13];
    if (isbf) {
        head_body<__hip_bfloat16>(b, t, gpart,
            (const __hip_bfloat16*)scaf, (const __hip_bfloat16*)W_sc, (const __hip_bfloat16*)b_sc,
            (const __hip_bfloat16*)gp_w1, (const __hip_bfloat16*)gp_b1,
            (const __hip_bfloat16*)gp_w2, (const __hip_bfloat16*)gp_b2,
            (const __hip_bfloat16*)out_w1, (const __hip_bfloat16*)out_b1,
            (const __hip_bfloat16*)out_w2, (const __hip_bfloat16*)out_b2,
            gin_s, sproj, scaf_s, red1, red2, z1g, z1s, cvec, hdn, outv);
    } else {
        head_body<float>(b, t, gpart,
            (const float*)scaf, (const float*)W_sc, (const float*)b_sc,
            (const float*)gp_w1, (const float*)gp_b1,
            (const float*)gp_w2, (const float*)gp_b2,
            (const float*)out_w1, (const float*)out_b1,
            (const float*)out_w2, (const float*)out_b2,
            gin_s, sproj, scaf_s, red1, red2, z1g, z1s, cvec, hdn, outv);
    }
    __syncthreads();
    if (t < 13) {
        if (isbf) ((__hip_bfloat16*)out)[b * 13 + t] = __float2bfloat16(outv[t]);
        else      ((float*)out)[b * 13 + t] = outv[t];
    }
}

extern "C" void kernel_launch(void* const* d_in, const int* in_sizes, int n_in,
                              void* d_out, int out_size, void* d_ws, size_t ws_size,
                              hipStream_t stream) {
    (void)in_sizes; (void)n_in; (void)out_size; (void)ws_size;
    const void* nf     = d_in[0];
    const int*  adj    = (const int*)d_in[2];
    const void* scaf   = d_in[3];
    const void* W_node = d_in[4];
    const void* b_node = d_in[5];
    const void* gat_W  = d_in[6];
    const void* gat_a  = d_in[7];
    const void* W_sc   = d_in[8];
    const void* b_sc   = d_in[9];
    const void* gp_w1  = d_in[10];
    const void* gp_b1  = d_in[11];
    const void* gp_w2  = d_in[12];
    const void* gp_b2  = d_in[13];
    const void* out_w1 = d_in[14];
    const void* out_b1 = d_in[15];
    const void* out_w2 = d_in[16];
    const void* out_b2 = d_in[17];

    float* ws    = (float*)d_ws;
    float* x     = ws;                      // 1048576 f32
    float* h     = ws + 1048576;            // 1048576 f32
    float* s1    = ws + 2097152;            // 4096
    float* s2    = s1 + 4096;               // 4096
    float* gpart = s2 + 4096;               // 131072

    for (int l = 0; l < 3; ++l) {
        k_gat<<<512, 256, 0, stream>>>(x, gat_W, gat_a, l,
                                       nf, W_node, b_node, (l == 0) ? 1 : 0,
                                       h, s1, s2);
        k_attn<<<512, 256, 0, stream>>>(h, s1, s2, adj, x, gpart, (l == 2) ? 1 : 0);
    }
    k_head<<<32, 256, 0, stream>>>(gpart, scaf, W_sc, b_sc, gp_w1, gp_b1, gp_w2, gp_b2,
                                   out_w1, out_b1, out_w2, out_b2, d_out, W_node);
}